// Round 16
// baseline (138.859 us; speedup 1.0000x reference)
//
#include <hip/hip_runtime.h>

// NeRF hierarchical sampler: 16 lanes per ray, 4 rays per wave64, 2 waves/block.
// All LDS traffic is wave-private (16-lane ray groups) -> no barriers needed.
// Cross-lane entirely via DPP in the sort: xor1=quad_perm 0xB1, xor2=quad_perm
// 0x4E, xor8=row_ror:8, xor4={row_ror:12 for lanes bit2=0, row_ror:4 for bit2=1}
// (row_ror:N = lane i reads lane (i-N)&15, same direction as row_shr; R14 had
// the select inverted). Scans via row_shr DPP. No ds_swizzle in the sort.
// Search levels 1-2 are register broadcasts (cdf[16/32/48] via shfl).
// Outputs via wave-contiguous nontemporal stores (z routed through LDS).
// org/dir loads hoisted to kernel top so their latency hides under the sort.
// Per-ray LDS (RSTR=324 floats, 16B-aligned):
//   [0..191]   srt  : staging (coarse 64 + fine 128), later the sorted 192
//   [192..255] cdfB : cdf[1..64]  (cdf[0]=0 handled implicitly: u>=0 always)
//   [256..320] edg  : 65-entry z_edges
#define RPW 4          // rays per wave
#define RPB 8          // rays per block (2 waves * 4)
#define RSTR 324       // per-ray LDS stride (floats); 324*4B = 1296B (16B mult)

typedef float vf4 __attribute__((ext_vector_type(4)));

template<int CTRL, bool BC>
__device__ __forceinline__ float updpp(float old, float x) {
    return __int_as_float(__builtin_amdgcn_update_dpp(
        __float_as_int(old), __float_as_int(x), CTRL, 0xF, 0xF, BC));
}

// One bitonic substage of the 256-element network, row-major 16 elems/lane.
// e = 16*sl + h; asc(e) = ((e&K)==0); partner = e ^ J.
template<int K, int J>
__device__ __forceinline__ void substage(float (&y)[16], const int sl) {
    if constexpr (J >= 16) {                     // cross-lane: lm = J/16 in {1,2,4,8}
        constexpr int lm = J >> 4;
        const bool uasc = ((sl & (K >> 4)) == 0);          // K >= 32 here
        const bool lo4  = ((sl & 4) == 0);                 // for the xor4 select
        #pragma unroll
        for (int h = 0; h < 16; ++h) {
            float p;
            if constexpr (lm == 1)      p = updpp<0xB1, true>(0.0f, y[h]); // xor1
            else if constexpr (lm == 2) p = updpp<0x4E, true>(0.0f, y[h]); // xor2
            else if constexpr (lm == 8) p = updpp<0x128,true>(0.0f, y[h]); // xor8
            else {                                                          // xor4
                float r4  = updpp<0x124,true>(0.0f, y[h]);  // lane i <- (i-4)&15
                float r12 = updpp<0x12C,true>(0.0f, y[h]);  // lane i <- (i+4)&15
                p = lo4 ? r12 : r4;                         // partner i^4
            }
            const bool tmin = (((sl & lm) == 0) == uasc);
            y[h] = tmin ? fminf(y[h], p) : fmaxf(y[h], p);
        }
    } else {                                     // in-register pairs (h, h^J)
        bool dirlane = true;
        if constexpr (K == 16)      dirlane = ((sl & 1) == 0);        // e&16
        else if constexpr (K >= 32) dirlane = ((sl & (K >> 4)) == 0); // e&K
        #pragma unroll
        for (int h = 0; h < 16; ++h) {
            if ((h & J) == 0) {
                const int b = h ^ J;             // compile-time after unroll
                bool dr;
                if constexpr (K <= 8) dr = ((h & K) == 0);
                else                  dr = dirlane;
                float lo_ = fminf(y[h], y[b]);
                float hi_ = fmaxf(y[h], y[b]);
                y[h] = dr ? lo_ : hi_;
                y[b] = dr ? hi_ : lo_;
            }
        }
    }
}

__global__ __launch_bounds__(128) void hier_sampler(
    const float* __restrict__ org, const float* __restrict__ dir,
    const float* __restrict__ dens, const float* __restrict__ trand,
    const float* __restrict__ uu, float* __restrict__ out_pts,
    float* __restrict__ out_z)
{
    const int tid  = threadIdx.x;
    const int sl   = tid & 15;                 // sub-lane within ray group
    const int rloc = tid >> 4;                 // local ray id in block, 0..7
    const int ray  = blockIdx.x * RPB + rloc;

    __shared__ __align__(16) float lds[RPB * RSTR];
    float* srt  = &lds[rloc * RSTR];
    float* cdfB = srt + 192;
    float* edg  = srt + 256;

    // ---- issue ALL global loads up front; latency hides under compute ----
    const float4 t4 = ((const float4*)trand)[(size_t)ray * 16 + sl];
    const float4 d4 = ((const float4*)dens )[(size_t)ray * 16 + sl];
    const float4 ua = ((const float4*)uu)[(size_t)ray*32 + 2*sl];
    const float4 ub = ((const float4*)uu)[(size_t)ray*32 + 2*sl + 1];
    const float ox = org[(size_t)ray*3+0], oy = org[(size_t)ray*3+1], oz = org[(size_t)ray*3+2];
    const float dx = dir[(size_t)ray*3+0], dy = dir[(size_t)ray*3+1], dz = dir[(size_t)ray*3+2];

    // ---- coarse stratified sampling: 4 samples/lane, j = 4*sl+m ----
    const float step = 4.0f / 63.0f;
    const float tarr[4] = {t4.x, t4.y, t4.z, t4.w};
    const float darr[4] = {d4.x, d4.y, d4.z, d4.w};
    float zv[4];
    #pragma unroll
    for (int m = 0; m < 4; ++m) {
        int j = 4*sl + m;
        float zg = 2.0f + step * (float)j;
        float lo = (j == 0)  ? 2.0f : (zg - 0.5f*step);   // mids are zg +- step/2
        float up = (j == 63) ? 6.0f : (zg + 0.5f*step);
        zv[m] = lo + (up - lo) * tarr[m];
    }
    float znext0 = updpp<0x101,true>(0.0f, zv[0]);        // shfl_down 1 (sl15 masked)
    float delta[4] = { zv[1]-zv[0], zv[2]-zv[1], zv[3]-zv[2],
                       (sl == 15) ? 1e10f : (znext0 - zv[3]) };

    // ---- transmittance weights (in-lane 4 + cross-lane 16 scans) ----
    float a[4], pp[4];
    {
        float run = 1.0f;
        #pragma unroll
        for (int m = 0; m < 4; ++m) {
            a[m] = 1.0f - __expf(-darr[m] * delta[m]);
            run *= (1.0f - a[m] + 1e-10f);
            pp[m] = run;                        // in-lane inclusive product
        }
    }
    // Hillis-Steele inclusive product scan over 16 lanes, identity=1.0
    float P = pp[3];
    P *= updpp<0x111,false>(1.0f, P);
    P *= updpp<0x112,false>(1.0f, P);
    P *= updpp<0x114,false>(1.0f, P);
    P *= updpp<0x118,false>(1.0f, P);
    float E = updpp<0x111,false>(1.0f, P);      // exclusive; sl==0 -> 1.0

    float sw[4];
    {
        float acc = 0.0f;
        #pragma unroll
        for (int m = 0; m < 4; ++m) {
            float T = (m == 0) ? E : E * pp[m-1];   // exclusive cumprod at j
            acc += a[m]*T + 1e-5f;                  // w + 1e-5, in-lane cumsum
            sw[m] = acc;
        }
    }
    // inclusive sum scan over 16 lanes, identity=0.0
    float S = sw[3];
    S += updpp<0x111,false>(0.0f, S);
    S += updpp<0x112,false>(0.0f, S);
    S += updpp<0x114,false>(0.0f, S);
    S += updpp<0x118,false>(0.0f, S);
    float Es  = updpp<0x111,false>(0.0f, S);    // exclusive; sl==0 -> 0
    float tot = __shfl(S, 15, 16);
    float itot = 1.0f / tot;

    *(float4*)(cdfB + 4*sl) = make_float4((Es+sw[0])*itot, (Es+sw[1])*itot,
                                          (Es+sw[2])*itot, (Es+sw[3])*itot);
    // register copies of cdfB[16], cdfB[32], cdfB[48] for search levels 0-1
    float bb  = Es + sw[0];
    float c16 = __shfl(bb, 4, 16)  * itot;      // cdfB[16]
    float c32 = __shfl(bb, 8, 16)  * itot;      // cdfB[32]
    float c48 = __shfl(bb, 12, 16) * itot;      // cdfB[48]

    // ---- z_edges ----
    float zp3 = updpp<0x111,true>(0.0f, zv[3]); // shfl_up 1 (sl0 masked)
    float ej0 = (sl == 0) ? (1.5f*zv[0] - 0.5f*zv[1]) : 0.5f*(zp3 + zv[0]);
    *(float4*)(edg + 4*sl) = make_float4(ej0, 0.5f*(zv[0]+zv[1]),
                                         0.5f*(zv[1]+zv[2]), 0.5f*(zv[2]+zv[3]));
    if (sl == 15) edg[64] = 1.5f*zv[3] - 0.5f*zv[2];
    // ---- stage coarse for sort ----
    *(float4*)(srt + 4*sl) = make_float4(zv[0], zv[1], zv[2], zv[3]);

    // ---- inverse-CDF fine sampling: 8 u's per lane ----
    // searchsorted(cdf65, u, 'right') = 1 + searchsorted_right(cdfB, u) since
    // cdf[0]=0 <= u always. lo in [0,64] after 7 steps; first 2 from registers.
    const float uarr[8] = {ua.x,ua.y,ua.z,ua.w, ub.x,ub.y,ub.z,ub.w};
    float fz[8];
    #pragma unroll
    for (int t = 0; t < 8; ++t) {
        float u = uarr[t];
        // level 0: m=32 -> c32; level 1: m=48 or 16 -> registers
        bool d0 = (c32 <= u);
        int  lo = d0 ? 33 : 0;
        int  hi = d0 ? 64 : 32;
        float cm1 = d0 ? c48 : c16;
        int  m1 = (lo + hi) >> 1;               // 48 or 16
        bool d1 = (cm1 <= u);
        lo = d1 ? m1 + 1 : lo;
        hi = d1 ? hi : m1;
        #pragma unroll
        for (int it = 0; it < 5; ++it) {
            int m = (lo + hi) >> 1;
            bool c = cdfB[m] <= u;
            lo = c ? m+1 : lo;
            hi = c ? hi  : m;
        }
        int below = lo;                          // = clip(inds-1) in [0,64]
        int above = (lo < 64) ? lo + 1 : 64;     // = clip(inds)   in [1,64]
        int bm1   = (below > 0) ? below - 1 : 0;
        float c0 = cdfB[bm1];
        if (below == 0) c0 = 0.0f;               // cdf[0] = 0
        float c1 = cdfB[above - 1];
        float e0 = edg[below], e1 = edg[above];
        float dn = c1 - c0;
        if (dn < 1e-5f) dn = 1.0f;
        float tt = (u - c0) / dn;
        fz[t] = e0 + tt * (e1 - e0);
    }
    *(float4*)(srt + 64 + 8*sl)     = make_float4(fz[0],fz[1],fz[2],fz[3]);
    *(float4*)(srt + 64 + 8*sl + 4) = make_float4(fz[4],fz[5],fz[6],fz[7]);

    // ---- load sort layout: y[h] = element 16*sl + h (pads 192..255 = 1e30) ----
    float y[16];
    if (sl < 12) {
        #pragma unroll
        for (int tq = 0; tq < 4; ++tq) {
            float4 v = *(const float4*)(srt + 16*sl + 4*tq);
            y[4*tq+0]=v.x; y[4*tq+1]=v.y; y[4*tq+2]=v.z; y[4*tq+3]=v.w;
        }
    } else {
        #pragma unroll
        for (int h = 0; h < 16; ++h) y[h] = 1.0e30f;
    }

    // ---- bitonic sort of 256: all 36 substages with compile-time (K,J) ----
    substage<2,1>(y, sl);

    substage<4,2>(y, sl);   substage<4,1>(y, sl);

    substage<8,4>(y, sl);   substage<8,2>(y, sl);   substage<8,1>(y, sl);

    substage<16,8>(y, sl);  substage<16,4>(y, sl);  substage<16,2>(y, sl);
    substage<16,1>(y, sl);

    substage<32,16>(y, sl); substage<32,8>(y, sl);  substage<32,4>(y, sl);
    substage<32,2>(y, sl);  substage<32,1>(y, sl);

    substage<64,32>(y, sl); substage<64,16>(y, sl); substage<64,8>(y, sl);
    substage<64,4>(y, sl);  substage<64,2>(y, sl);  substage<64,1>(y, sl);

    substage<128,64>(y, sl); substage<128,32>(y, sl); substage<128,16>(y, sl);
    substage<128,8>(y, sl);  substage<128,4>(y, sl);  substage<128,2>(y, sl);
    substage<128,1>(y, sl);

    substage<256,128>(y, sl); substage<256,64>(y, sl); substage<256,32>(y, sl);
    substage<256,16>(y, sl);  substage<256,8>(y, sl);  substage<256,4>(y, sl);
    substage<256,2>(y, sl);   substage<256,1>(y, sl);

    // ---- write sorted to LDS ----
    if (sl < 12) {
        #pragma unroll
        for (int tq = 0; tq < 4; ++tq) {
            *(float4*)(srt + 16*sl + 4*tq) =
                make_float4(y[4*tq],y[4*tq+1],y[4*tq+2],y[4*tq+3]);
        }
    }

    // ---- z emit, coalesced: 48 float4 chunks/ray, lane sl takes chunk it*16+sl
    // (consecutive lanes -> consecutive 16B -> wave-contiguous NT stores) ----
    {
        float* zb = out_z + (size_t)ray * 192;
        #pragma unroll
        for (int it = 0; it < 3; ++it) {
            int c = it * 16 + sl;               // 0..47
            vf4 v = *(const vf4*)(srt + 4*c);   // 16B/lane, stride 16B: conflict-free
            __builtin_nontemporal_store(v, (vf4*)(zb + 4*c));
        }
    }

    // ---- emit points: per-ray group, 144 float4 chunks = 9 iterations ----
    float* pbase = out_pts + (size_t)ray * 576;
    #pragma unroll
    for (int it = 0; it < 9; ++it) {
        int i  = it*16 + sl;                // chunk id 0..143, covers idx 4i..4i+3
        int q  = i / 3;
        int c0 = i - 3*q;                   // idx%3
        int k0 = i + q;                     // idx/3
        const float* zp = srt + k0;         // paired reads -> ds_read2_b32
        float z0 = zp[0];
        float z1 = zp[1];
        // m=0: ch=c0,z0    m=3: ch=c0,z1
        float o0  = (c0==0)?ox:((c0==1)?oy:oz);
        float dd0 = (c0==0)?dx:((c0==1)?dy:dz);
        float v0 = fmaf(dd0, z0, o0);
        float v3 = fmaf(dd0, z1, o0);
        // m=1: cm=c0+1 (wraps at 3 -> z1)
        int   c1i = (c0==2)?0:(c0+1);
        float zz1 = (c0==2)?z1:z0;
        float o1  = (c1i==0)?ox:((c1i==1)?oy:oz);
        float dd1 = (c1i==0)?dx:((c1i==1)?dy:dz);
        float v1 = fmaf(dd1, zz1, o1);
        // m=2: cm=c0+2 (wraps for c0>=1 -> z1)
        int   c2i = (c0==0)?2:(c0-1);
        float zz2 = (c0==0)?z0:z1;
        float o2  = (c2i==0)?ox:((c2i==1)?oy:oz);
        float dd2 = (c2i==0)?dx:((c2i==1)?dy:dz);
        float v2 = fmaf(dd2, zz2, o2);
        vf4 v = {v0, v1, v2, v3};
        __builtin_nontemporal_store(v, (vf4*)(pbase + 4*i));
    }
}

extern "C" void kernel_launch(void* const* d_in, const int* in_sizes, int n_in,
                              void* d_out, int out_size, void* d_ws, size_t ws_size,
                              hipStream_t stream) {
    const float* org   = (const float*)d_in[0];
    const float* dir   = (const float*)d_in[1];
    const float* dens  = (const float*)d_in[2];
    const float* trand = (const float*)d_in[3];
    const float* uv    = (const float*)d_in[4];
    int B = in_sizes[0] / 3;   // 131072

    float* out_pts = (float*)d_out;
    float* out_z   = out_pts + (size_t)B * 576;

    dim3 grid(B / RPB), block(128);
    hipLaunchKernelGGL(hier_sampler, grid, block, 0, stream,
                       org, dir, dens, trand, uv, out_pts, out_z);
}

// Round 19
// 118.643 us; speedup vs baseline: 1.1704x; 1.1704x over previous
//
#include <hip/hip_runtime.h>

// NeRF hierarchical sampler: 16 lanes per ray, 4 rays per wave64, 2 waves/block.
// Sort = merge decomposition: fine 128 sorted DESCENDING in registers (8/lane,
// no LDS pre-staging round trip), then [coarse asc 64][fine desc 128][-1e30 x64]
// is bitonic -> single 8-substage ascending bitonic merge at 16/lane.
// All cross-lane via DPP (xor1=quad_perm 0xB1, xor2=0x4E, xor8=row_ror:8,
// xor4=row_ror:12/row_ror:4 select). Scans via row_shr DPP.
// Search levels 1-2 are register broadcasts (cdf[16/32/48] via shfl).
// Outputs via wave-contiguous nontemporal stores (z routed through LDS).
// Per-ray LDS (RSTR=324 floats, 16B-aligned):
//   [0..191]   srt  : coarse(0..63) + fine-sorted(64..191), later sorted 192
//   [192..255] cdfB : cdf[1..64]  (cdf[0]=0 handled implicitly: u>=0 always)
//   [256..320] edg  : 65-entry z_edges
#define RPW 4
#define RPB 8
#define RSTR 324

typedef float vf4 __attribute__((ext_vector_type(4)));

template<int CTRL, bool BC>
__device__ __forceinline__ float updpp(float old, float x) {
    return __int_as_float(__builtin_amdgcn_update_dpp(
        __float_as_int(old), __float_as_int(x), CTRL, 0xF, 0xF, BC));
}

// cross-lane xor within 16-lane row, distance LM in {1,2,4,8}
template<int LM>
__device__ __forceinline__ float xl(float x, const bool lo4) {
    if constexpr (LM == 1)      return updpp<0xB1, true>(0.0f, x);
    else if constexpr (LM == 2) return updpp<0x4E, true>(0.0f, x);
    else if constexpr (LM == 8) return updpp<0x128,true>(0.0f, x);
    else {
        float r4  = updpp<0x124,true>(0.0f, x);   // lane i <- (i-4)&15
        float r12 = updpp<0x12C,true>(0.0f, x);   // lane i <- (i+4)&15
        return lo4 ? r12 : r4;                    // partner i^4
    }
}

#define CE(a, b, dir) { float _lo = fminf(a, b), _hi = fmaxf(a, b); \
                        a = (dir) ? _lo : _hi; b = (dir) ? _hi : _lo; }

// Fine sort substage: 128 elements DESCENDING, 8/lane, e = 8*sl + h.
// Inverted network: asc(e) = ((e&K)!=0); tmin(e) = (asc == ((e&J)==0)).
template<int K, int J>
__device__ __forceinline__ void substageF(float (&f)[8], const int sl) {
    if constexpr (J >= 8) {                      // cross-lane: lm = J/8
        constexpr int lm = J >> 3;
        const bool uasc = ((sl & (K >> 3)) != 0);          // K >= 16 here
        const bool lo4  = ((sl & 4) == 0);
        #pragma unroll
        for (int h = 0; h < 8; ++h) {
            float p = xl<lm>(f[h], lo4);
            const bool tmin = (uasc == ((sl & lm) == 0));
            f[h] = tmin ? fminf(f[h], p) : fmaxf(f[h], p);
        }
    } else {
        bool dirlane = true;
        if constexpr (K == 8)       dirlane = ((sl & 1) != 0);
        else if constexpr (K >= 16) dirlane = ((sl & (K >> 3)) != 0);
        #pragma unroll
        for (int h = 0; h < 8; ++h) {
            if ((h & J) == 0) {
                const int b = h ^ J;
                bool dr;
                if constexpr (K <= 4) dr = ((h & K) != 0);
                else                  dr = dirlane;
                CE(f[h], f[b], dr);
            }
        }
    }
}

// Merge substage: 256 elements, 16/lane, e = 16*sl + h, ascending everywhere.
template<int J>
__device__ __forceinline__ void substageM(float (&y)[16], const int sl) {
    if constexpr (J >= 16) {                     // cross-lane: lm = J/16
        constexpr int lm = J >> 4;
        const bool lo4 = ((sl & 4) == 0);
        #pragma unroll
        for (int h = 0; h < 16; ++h) {
            float p = xl<lm>(y[h], lo4);
            const bool tmin = ((sl & lm) == 0);
            y[h] = tmin ? fminf(y[h], p) : fmaxf(y[h], p);
        }
    } else {
        #pragma unroll
        for (int h = 0; h < 16; ++h) {
            if ((h & J) == 0) {
                const int b = h ^ J;
                CE(y[h], y[b], true);
            }
        }
    }
}

__global__ __launch_bounds__(128) void hier_sampler(
    const float* __restrict__ org, const float* __restrict__ dir,
    const float* __restrict__ dens, const float* __restrict__ trand,
    const float* __restrict__ uu, float* __restrict__ out_pts,
    float* __restrict__ out_z)
{
    const int tid  = threadIdx.x;
    const int sl   = tid & 15;
    const int rloc = tid >> 4;
    const int ray  = blockIdx.x * RPB + rloc;

    __shared__ __align__(16) float lds[RPB * RSTR];
    float* srt  = &lds[rloc * RSTR];
    float* cdfB = srt + 192;
    float* edg  = srt + 256;

    // ---- issue ALL global loads up front ----
    const float4 t4 = ((const float4*)trand)[(size_t)ray * 16 + sl];
    const float4 d4 = ((const float4*)dens )[(size_t)ray * 16 + sl];
    const float4 ua = ((const float4*)uu)[(size_t)ray*32 + 2*sl];
    const float4 ub = ((const float4*)uu)[(size_t)ray*32 + 2*sl + 1];
    const float ox = org[(size_t)ray*3+0], oy = org[(size_t)ray*3+1], oz = org[(size_t)ray*3+2];
    const float dx = dir[(size_t)ray*3+0], dy = dir[(size_t)ray*3+1], dz = dir[(size_t)ray*3+2];

    // ---- coarse stratified sampling: 4 samples/lane, j = 4*sl+m ----
    const float step = 4.0f / 63.0f;
    const float tarr[4] = {t4.x, t4.y, t4.z, t4.w};
    const float darr[4] = {d4.x, d4.y, d4.z, d4.w};
    float zv[4];
    #pragma unroll
    for (int m = 0; m < 4; ++m) {
        int j = 4*sl + m;
        float zg = 2.0f + step * (float)j;
        float lo = (j == 0)  ? 2.0f : (zg - 0.5f*step);
        float up = (j == 63) ? 6.0f : (zg + 0.5f*step);
        zv[m] = lo + (up - lo) * tarr[m];
    }
    float znext0 = updpp<0x101,true>(0.0f, zv[0]);        // shfl_down 1
    float delta[4] = { zv[1]-zv[0], zv[2]-zv[1], zv[3]-zv[2],
                       (sl == 15) ? 1e10f : (znext0 - zv[3]) };

    // ---- transmittance weights (in-lane 4 + cross-lane 16 scans) ----
    float a[4], pp[4];
    {
        float run = 1.0f;
        #pragma unroll
        for (int m = 0; m < 4; ++m) {
            a[m] = 1.0f - __expf(-darr[m] * delta[m]);
            run *= (1.0f - a[m] + 1e-10f);
            pp[m] = run;
        }
    }
    float P = pp[3];
    P *= updpp<0x111,false>(1.0f, P);
    P *= updpp<0x112,false>(1.0f, P);
    P *= updpp<0x114,false>(1.0f, P);
    P *= updpp<0x118,false>(1.0f, P);
    float E = updpp<0x111,false>(1.0f, P);      // exclusive; sl==0 -> 1.0

    float sw[4];
    {
        float acc = 0.0f;
        #pragma unroll
        for (int m = 0; m < 4; ++m) {
            float T = (m == 0) ? E : E * pp[m-1];
            acc += a[m]*T + 1e-5f;
            sw[m] = acc;
        }
    }
    float S = sw[3];
    S += updpp<0x111,false>(0.0f, S);
    S += updpp<0x112,false>(0.0f, S);
    S += updpp<0x114,false>(0.0f, S);
    S += updpp<0x118,false>(0.0f, S);
    float Es  = updpp<0x111,false>(0.0f, S);
    float tot = __shfl(S, 15, 16);
    float itot = 1.0f / tot;

    *(float4*)(cdfB + 4*sl) = make_float4((Es+sw[0])*itot, (Es+sw[1])*itot,
                                          (Es+sw[2])*itot, (Es+sw[3])*itot);
    float bb  = Es + sw[0];
    float c16 = __shfl(bb, 4, 16)  * itot;
    float c32 = __shfl(bb, 8, 16)  * itot;
    float c48 = __shfl(bb, 12, 16) * itot;

    // ---- z_edges ----
    float zp3 = updpp<0x111,true>(0.0f, zv[3]);
    float ej0 = (sl == 0) ? (1.5f*zv[0] - 0.5f*zv[1]) : 0.5f*(zp3 + zv[0]);
    *(float4*)(edg + 4*sl) = make_float4(ej0, 0.5f*(zv[0]+zv[1]),
                                         0.5f*(zv[1]+zv[2]), 0.5f*(zv[2]+zv[3]));
    if (sl == 15) edg[64] = 1.5f*zv[3] - 0.5f*zv[2];
    // ---- stage coarse (merged-elements 0..63, ascending) ----
    *(float4*)(srt + 4*sl) = make_float4(zv[0], zv[1], zv[2], zv[3]);

    // ---- inverse-CDF fine sampling: 8 u's per lane (= fine elems 8sl..8sl+7) --
    const float uarr[8] = {ua.x,ua.y,ua.z,ua.w, ub.x,ub.y,ub.z,ub.w};
    float fz[8];
    #pragma unroll
    for (int t = 0; t < 8; ++t) {
        float u = uarr[t];
        bool d0 = (c32 <= u);
        int  lo = d0 ? 33 : 0;
        int  hi = d0 ? 64 : 32;
        float cm1 = d0 ? c48 : c16;
        int  m1 = (lo + hi) >> 1;
        bool d1 = (cm1 <= u);
        lo = d1 ? m1 + 1 : lo;
        hi = d1 ? hi : m1;
        #pragma unroll
        for (int it = 0; it < 5; ++it) {
            int m = (lo + hi) >> 1;
            bool c = cdfB[m] <= u;
            lo = c ? m+1 : lo;
            hi = c ? hi  : m;
        }
        int below = lo;
        int above = (lo < 64) ? lo + 1 : 64;
        int bm1   = (below > 0) ? below - 1 : 0;
        float c0 = cdfB[bm1];
        if (below == 0) c0 = 0.0f;
        float c1 = cdfB[above - 1];
        float e0 = edg[below], e1 = edg[above];
        float dn = c1 - c0;
        if (dn < 1e-5f) dn = 1.0f;
        float tt = (u - c0) / dn;
        fz[t] = e0 + tt * (e1 - e0);
    }

    // ---- bitonic sort of fine 128 DESCENDING, in registers (8/lane) ----
    substageF<2,1>(fz, sl);
    substageF<4,2>(fz, sl);    substageF<4,1>(fz, sl);
    substageF<8,4>(fz, sl);    substageF<8,2>(fz, sl);    substageF<8,1>(fz, sl);
    substageF<16,8>(fz, sl);   substageF<16,4>(fz, sl);   substageF<16,2>(fz, sl);
    substageF<16,1>(fz, sl);
    substageF<32,16>(fz, sl);  substageF<32,8>(fz, sl);   substageF<32,4>(fz, sl);
    substageF<32,2>(fz, sl);   substageF<32,1>(fz, sl);
    substageF<64,32>(fz, sl);  substageF<64,16>(fz, sl);  substageF<64,8>(fz, sl);
    substageF<64,4>(fz, sl);   substageF<64,2>(fz, sl);   substageF<64,1>(fz, sl);
    substageF<128,64>(fz, sl); substageF<128,32>(fz, sl); substageF<128,16>(fz, sl);
    substageF<128,8>(fz, sl);  substageF<128,4>(fz, sl);  substageF<128,2>(fz, sl);
    substageF<128,1>(fz, sl);

    // stage fine-sorted at merged-elements 64..191
    *(float4*)(srt + 64 + 8*sl)     = make_float4(fz[0],fz[1],fz[2],fz[3]);
    *(float4*)(srt + 64 + 8*sl + 4) = make_float4(fz[4],fz[5],fz[6],fz[7]);

    // ---- load merge layout: y[h] = merged-element 16*sl+h ----
    // [coarse asc 64][fine desc 128][-1e30 x 64] is bitonic.
    float y[16];
    if (sl < 12) {
        #pragma unroll
        for (int tq = 0; tq < 4; ++tq) {
            float4 v = *(const float4*)(srt + 16*sl + 4*tq);
            y[4*tq+0]=v.x; y[4*tq+1]=v.y; y[4*tq+2]=v.z; y[4*tq+3]=v.w;
        }
    } else {
        #pragma unroll
        for (int h = 0; h < 16; ++h) y[h] = -1.0e30f;
    }

    // ---- bitonic merge of 256, ascending: 8 substages ----
    substageM<128>(y, sl); substageM<64>(y, sl); substageM<32>(y, sl);
    substageM<16>(y, sl);  substageM<8>(y, sl);  substageM<4>(y, sl);
    substageM<2>(y, sl);   substageM<1>(y, sl);

    // pads (-1e30) occupy elements 0..63; real ranks 0..191 at elements 64..255.
    if (sl >= 4) {
        #pragma unroll
        for (int tq = 0; tq < 4; ++tq) {
            *(float4*)(srt + 16*(sl-4) + 4*tq) =
                make_float4(y[4*tq],y[4*tq+1],y[4*tq+2],y[4*tq+3]);
        }
    }

    // ---- z emit, coalesced: 48 float4 chunks/ray ----
    {
        float* zb = out_z + (size_t)ray * 192;
        #pragma unroll
        for (int it = 0; it < 3; ++it) {
            int c = it * 16 + sl;
            vf4 v = *(const vf4*)(srt + 4*c);
            __builtin_nontemporal_store(v, (vf4*)(zb + 4*c));
        }
    }

    // ---- emit points: per-ray group, 144 float4 chunks = 9 iterations ----
    float* pbase = out_pts + (size_t)ray * 576;
    #pragma unroll
    for (int it = 0; it < 9; ++it) {
        int i  = it*16 + sl;
        int q  = i / 3;
        int c0 = i - 3*q;
        int k0 = i + q;
        const float* zp = srt + k0;
        float z0 = zp[0];
        float z1 = zp[1];
        float o0  = (c0==0)?ox:((c0==1)?oy:oz);
        float dd0 = (c0==0)?dx:((c0==1)?dy:dz);
        float v0 = fmaf(dd0, z0, o0);
        float v3 = fmaf(dd0, z1, o0);
        int   c1i = (c0==2)?0:(c0+1);
        float zz1 = (c0==2)?z1:z0;
        float o1  = (c1i==0)?ox:((c1i==1)?oy:oz);
        float dd1 = (c1i==0)?dx:((c1i==1)?dy:dz);
        float v1 = fmaf(dd1, zz1, o1);
        int   c2i = (c0==0)?2:(c0-1);
        float zz2 = (c0==0)?z0:z1;
        float o2  = (c2i==0)?ox:((c2i==1)?oy:oz);
        float dd2 = (c2i==0)?dx:((c2i==1)?dy:dz);
        float v2 = fmaf(dd2, zz2, o2);
        vf4 v = {v0, v1, v2, v3};
        __builtin_nontemporal_store(v, (vf4*)(pbase + 4*i));
    }
}

extern "C" void kernel_launch(void* const* d_in, const int* in_sizes, int n_in,
                              void* d_out, int out_size, void* d_ws, size_t ws_size,
                              hipStream_t stream) {
    const float* org   = (const float*)d_in[0];
    const float* dir   = (const float*)d_in[1];
    const float* dens  = (const float*)d_in[2];
    const float* trand = (const float*)d_in[3];
    const float* uv    = (const float*)d_in[4];
    int B = in_sizes[0] / 3;   // 131072

    float* out_pts = (float*)d_out;
    float* out_z   = out_pts + (size_t)B * 576;

    dim3 grid(B / RPB), block(128);
    hipLaunchKernelGGL(hier_sampler, grid, block, 0, stream,
                       org, dir, dens, trand, uv, out_pts, out_z);
}

// Round 21
// 113.969 us; speedup vs baseline: 1.2184x; 1.0410x over previous
//
#include <hip/hip_runtime.h>

// NeRF hierarchical sampler: 16 lanes per ray, 4 rays per wave64, 2 waves/block.
// Sort = merge decomposition: fine 128 sorted DESCENDING in registers (8/lane),
// then [coarse asc 64][fine desc 128][-1e30 x64] is bitonic -> 8-substage
// ascending bitonic merge at 16/lane. All cross-lane via DPP.
// Search levels 1-2 from register broadcasts; final cdf/edge lookups as PAIRED
// ds_read2 (common base + static offsets; clamp cases fixed by selects).
// Emit: 3-phase unroll, o/d selects hoisted per phase. c0=(sl+p) mod 3 computed
// via smod=sl%3 then ONE conditional subtract (R20 used two subtracts on sl+p
// which fails for sl+p>=9 -> wrong channels; absmax 39).
// Outputs via wave-contiguous nontemporal stores (z routed through LDS).
// Per-ray LDS (RSTR=324 floats, 16B-aligned):
//   [0..191]   srt  : coarse(0..63) + fine-sorted(64..191), later sorted 192
//   [192..255] cdfB : cdf[1..64]
//   [256..320] edg  : 65-entry z_edges   (321..323 = padding, absorbs overreads)
#define RPW 4
#define RPB 8
#define RSTR 324

typedef float vf4 __attribute__((ext_vector_type(4)));

template<int CTRL, bool BC>
__device__ __forceinline__ float updpp(float old, float x) {
    return __int_as_float(__builtin_amdgcn_update_dpp(
        __float_as_int(old), __float_as_int(x), CTRL, 0xF, 0xF, BC));
}

// cross-lane xor within 16-lane row, distance LM in {1,2,4,8}
template<int LM>
__device__ __forceinline__ float xl(float x, const bool lo4) {
    if constexpr (LM == 1)      return updpp<0xB1, true>(0.0f, x);
    else if constexpr (LM == 2) return updpp<0x4E, true>(0.0f, x);
    else if constexpr (LM == 8) return updpp<0x128,true>(0.0f, x);
    else {
        float r4  = updpp<0x124,true>(0.0f, x);   // lane i <- (i-4)&15
        float r12 = updpp<0x12C,true>(0.0f, x);   // lane i <- (i+4)&15
        return lo4 ? r12 : r4;                    // partner i^4
    }
}

#define CE(a, b, dir) { float _lo = fminf(a, b), _hi = fmaxf(a, b); \
                        a = (dir) ? _lo : _hi; b = (dir) ? _hi : _lo; }

// Fine sort substage: 128 elements DESCENDING, 8/lane, e = 8*sl + h.
// Inverted network: asc(e) = ((e&K)!=0); tmin(e) = (asc == ((e&J)==0)).
template<int K, int J>
__device__ __forceinline__ void substageF(float (&f)[8], const int sl) {
    if constexpr (J >= 8) {                      // cross-lane: lm = J/8
        constexpr int lm = J >> 3;
        const bool uasc = ((sl & (K >> 3)) != 0);          // K >= 16 here
        const bool lo4  = ((sl & 4) == 0);
        #pragma unroll
        for (int h = 0; h < 8; ++h) {
            float p = xl<lm>(f[h], lo4);
            const bool tmin = (uasc == ((sl & lm) == 0));
            f[h] = tmin ? fminf(f[h], p) : fmaxf(f[h], p);
        }
    } else {
        bool dirlane = true;
        if constexpr (K == 8)       dirlane = ((sl & 1) != 0);
        else if constexpr (K >= 16) dirlane = ((sl & (K >> 3)) != 0);
        #pragma unroll
        for (int h = 0; h < 8; ++h) {
            if ((h & J) == 0) {
                const int b = h ^ J;
                bool dr;
                if constexpr (K <= 4) dr = ((h & K) != 0);
                else                  dr = dirlane;
                CE(f[h], f[b], dr);
            }
        }
    }
}

// Merge substage: 256 elements, 16/lane, e = 16*sl + h, ascending everywhere.
template<int J>
__device__ __forceinline__ void substageM(float (&y)[16], const int sl) {
    if constexpr (J >= 16) {                     // cross-lane: lm = J/16
        constexpr int lm = J >> 4;
        const bool lo4 = ((sl & 4) == 0);
        #pragma unroll
        for (int h = 0; h < 16; ++h) {
            float p = xl<lm>(y[h], lo4);
            const bool tmin = ((sl & lm) == 0);
            y[h] = tmin ? fminf(y[h], p) : fmaxf(y[h], p);
        }
    } else {
        #pragma unroll
        for (int h = 0; h < 16; ++h) {
            if ((h & J) == 0) {
                const int b = h ^ J;
                CE(y[h], y[b], true);
            }
        }
    }
}

__global__ __launch_bounds__(128) void hier_sampler(
    const float* __restrict__ org, const float* __restrict__ dir,
    const float* __restrict__ dens, const float* __restrict__ trand,
    const float* __restrict__ uu, float* __restrict__ out_pts,
    float* __restrict__ out_z)
{
    const int tid  = threadIdx.x;
    const int sl   = tid & 15;
    const int rloc = tid >> 4;
    const int ray  = blockIdx.x * RPB + rloc;

    __shared__ __align__(16) float lds[RPB * RSTR];
    float* srt  = &lds[rloc * RSTR];
    float* cdfB = srt + 192;
    float* edg  = srt + 256;

    // ---- issue ALL global loads up front ----
    const float4 t4 = ((const float4*)trand)[(size_t)ray * 16 + sl];
    const float4 d4 = ((const float4*)dens )[(size_t)ray * 16 + sl];
    const float4 ua = ((const float4*)uu)[(size_t)ray*32 + 2*sl];
    const float4 ub = ((const float4*)uu)[(size_t)ray*32 + 2*sl + 1];
    const float ox = org[(size_t)ray*3+0], oy = org[(size_t)ray*3+1], oz = org[(size_t)ray*3+2];
    const float dx = dir[(size_t)ray*3+0], dy = dir[(size_t)ray*3+1], dz = dir[(size_t)ray*3+2];

    // ---- coarse stratified sampling: 4 samples/lane, j = 4*sl+m ----
    const float step = 4.0f / 63.0f;
    const float tarr[4] = {t4.x, t4.y, t4.z, t4.w};
    const float darr[4] = {d4.x, d4.y, d4.z, d4.w};
    float zv[4];
    #pragma unroll
    for (int m = 0; m < 4; ++m) {
        int j = 4*sl + m;
        float zg = 2.0f + step * (float)j;
        float lo = (j == 0)  ? 2.0f : (zg - 0.5f*step);
        float up = (j == 63) ? 6.0f : (zg + 0.5f*step);
        zv[m] = lo + (up - lo) * tarr[m];
    }
    float znext0 = updpp<0x101,true>(0.0f, zv[0]);        // shfl_down 1
    float delta[4] = { zv[1]-zv[0], zv[2]-zv[1], zv[3]-zv[2],
                       (sl == 15) ? 1e10f : (znext0 - zv[3]) };

    // ---- transmittance weights (in-lane 4 + cross-lane 16 scans) ----
    float a[4], pp[4];
    {
        float run = 1.0f;
        #pragma unroll
        for (int m = 0; m < 4; ++m) {
            a[m] = 1.0f - __expf(-darr[m] * delta[m]);
            run *= (1.0f - a[m] + 1e-10f);
            pp[m] = run;
        }
    }
    float P = pp[3];
    P *= updpp<0x111,false>(1.0f, P);
    P *= updpp<0x112,false>(1.0f, P);
    P *= updpp<0x114,false>(1.0f, P);
    P *= updpp<0x118,false>(1.0f, P);
    float E = updpp<0x111,false>(1.0f, P);      // exclusive; sl==0 -> 1.0

    float sw[4];
    {
        float acc = 0.0f;
        #pragma unroll
        for (int m = 0; m < 4; ++m) {
            float T = (m == 0) ? E : E * pp[m-1];
            acc += a[m]*T + 1e-5f;
            sw[m] = acc;
        }
    }
    float S = sw[3];
    S += updpp<0x111,false>(0.0f, S);
    S += updpp<0x112,false>(0.0f, S);
    S += updpp<0x114,false>(0.0f, S);
    S += updpp<0x118,false>(0.0f, S);
    float Es  = updpp<0x111,false>(0.0f, S);
    float tot = __shfl(S, 15, 16);
    float itot = 1.0f / tot;

    *(float4*)(cdfB + 4*sl) = make_float4((Es+sw[0])*itot, (Es+sw[1])*itot,
                                          (Es+sw[2])*itot, (Es+sw[3])*itot);
    float bb  = Es + sw[0];
    float c16 = __shfl(bb, 4, 16)  * itot;
    float c32 = __shfl(bb, 8, 16)  * itot;
    float c48 = __shfl(bb, 12, 16) * itot;

    // ---- z_edges ----
    float zp3 = updpp<0x111,true>(0.0f, zv[3]);
    float ej0 = (sl == 0) ? (1.5f*zv[0] - 0.5f*zv[1]) : 0.5f*(zp3 + zv[0]);
    *(float4*)(edg + 4*sl) = make_float4(ej0, 0.5f*(zv[0]+zv[1]),
                                         0.5f*(zv[1]+zv[2]), 0.5f*(zv[2]+zv[3]));
    if (sl == 15) edg[64] = 1.5f*zv[3] - 0.5f*zv[2];
    // ---- stage coarse (merged-elements 0..63, ascending) ----
    *(float4*)(srt + 4*sl) = make_float4(zv[0], zv[1], zv[2], zv[3]);

    // ---- inverse-CDF fine sampling: 8 u's per lane (= fine elems 8sl..8sl+7) --
    const float uarr[8] = {ua.x,ua.y,ua.z,ua.w, ub.x,ub.y,ub.z,ub.w};
    float fz[8];
    #pragma unroll
    for (int t = 0; t < 8; ++t) {
        float u = uarr[t];
        bool d0 = (c32 <= u);
        int  lo = d0 ? 33 : 0;
        int  hi = d0 ? 64 : 32;
        float cm1 = d0 ? c48 : c16;
        int  m1 = (lo + hi) >> 1;
        bool d1 = (cm1 <= u);
        lo = d1 ? m1 + 1 : lo;
        hi = d1 ? hi : m1;
        #pragma unroll
        for (int it = 0; it < 5; ++it) {
            int m = (lo + hi) >> 1;
            bool c = cdfB[m] <= u;
            lo = c ? m+1 : lo;
            hi = c ? hi  : m;
        }
        // finals as paired reads: cb[0],cb[1] and eb[0],eb[1] (ds_read2).
        // Overreads land in written-or-discarded slots (in-bounds).
        int c0a = (lo > 0) ? lo - 1 : 0;
        const float* cb = cdfB + c0a;
        float w0 = cb[0], w1 = cb[1];
        float c0v = (lo == 0) ? 0.0f : w0;               // cdf[below]
        float c1v = (lo == 0 || lo == 64) ? w0 : w1;     // cdf[above]
        const float* eb = edg + lo;                      // below = lo
        float x0 = eb[0], x1 = eb[1];
        float e0 = x0;
        float e1 = (lo < 64) ? x1 : x0;                  // above = min(lo+1,64)
        float dn = c1v - c0v;
        if (dn < 1e-5f) dn = 1.0f;
        float tt = (u - c0v) / dn;
        fz[t] = e0 + tt * (e1 - e0);
    }

    // ---- bitonic sort of fine 128 DESCENDING, in registers (8/lane) ----
    substageF<2,1>(fz, sl);
    substageF<4,2>(fz, sl);    substageF<4,1>(fz, sl);
    substageF<8,4>(fz, sl);    substageF<8,2>(fz, sl);    substageF<8,1>(fz, sl);
    substageF<16,8>(fz, sl);   substageF<16,4>(fz, sl);   substageF<16,2>(fz, sl);
    substageF<16,1>(fz, sl);
    substageF<32,16>(fz, sl);  substageF<32,8>(fz, sl);   substageF<32,4>(fz, sl);
    substageF<32,2>(fz, sl);   substageF<32,1>(fz, sl);
    substageF<64,32>(fz, sl);  substageF<64,16>(fz, sl);  substageF<64,8>(fz, sl);
    substageF<64,4>(fz, sl);   substageF<64,2>(fz, sl);   substageF<64,1>(fz, sl);
    substageF<128,64>(fz, sl); substageF<128,32>(fz, sl); substageF<128,16>(fz, sl);
    substageF<128,8>(fz, sl);  substageF<128,4>(fz, sl);  substageF<128,2>(fz, sl);
    substageF<128,1>(fz, sl);

    // stage fine-sorted at merged-elements 64..191
    *(float4*)(srt + 64 + 8*sl)     = make_float4(fz[0],fz[1],fz[2],fz[3]);
    *(float4*)(srt + 64 + 8*sl + 4) = make_float4(fz[4],fz[5],fz[6],fz[7]);

    // ---- load merge layout: y[h] = merged-element 16*sl+h ----
    float y[16];
    if (sl < 12) {
        #pragma unroll
        for (int tq = 0; tq < 4; ++tq) {
            float4 v = *(const float4*)(srt + 16*sl + 4*tq);
            y[4*tq+0]=v.x; y[4*tq+1]=v.y; y[4*tq+2]=v.z; y[4*tq+3]=v.w;
        }
    } else {
        #pragma unroll
        for (int h = 0; h < 16; ++h) y[h] = -1.0e30f;
    }

    // ---- bitonic merge of 256, ascending: 8 substages ----
    substageM<128>(y, sl); substageM<64>(y, sl); substageM<32>(y, sl);
    substageM<16>(y, sl);  substageM<8>(y, sl);  substageM<4>(y, sl);
    substageM<2>(y, sl);   substageM<1>(y, sl);

    // pads (-1e30) occupy elements 0..63; real ranks 0..191 at elements 64..255.
    if (sl >= 4) {
        #pragma unroll
        for (int tq = 0; tq < 4; ++tq) {
            *(float4*)(srt + 16*(sl-4) + 4*tq) =
                make_float4(y[4*tq],y[4*tq+1],y[4*tq+2],y[4*tq+3]);
        }
    }

    // ---- z emit, coalesced: 48 float4 chunks/ray ----
    {
        float* zb = out_z + (size_t)ray * 192;
        #pragma unroll
        for (int it = 0; it < 3; ++it) {
            int c = it * 16 + sl;
            vf4 v = *(const vf4*)(srt + 4*c);
            __builtin_nontemporal_store(v, (vf4*)(zb + 4*c));
        }
    }

    // ---- emit points: 3 phases x 3 iterations; c0 = (smod+p) mod 3 with
    // smod = sl % 3 precomputed, ONE conditional subtract (max smod+p = 4) ----
    float* pbase = out_pts + (size_t)ray * 576;
    const int smod = sl % 3;
    #pragma unroll
    for (int p = 0; p < 3; ++p) {
        int c0p = smod + p;
        c0p -= (c0p >= 3) ? 3 : 0;              // (sl+p) mod 3
        float o0  = (c0p==0)?ox:((c0p==1)?oy:oz);
        float dd0 = (c0p==0)?dx:((c0p==1)?dy:dz);
        int   c1i = (c0p==2)?0:(c0p+1);
        float o1  = (c1i==0)?ox:((c1i==1)?oy:oz);
        float dd1 = (c1i==0)?dx:((c1i==1)?dy:dz);
        int   c2i = (c0p==0)?2:(c0p-1);
        float o2  = (c2i==0)?ox:((c2i==1)?oy:oz);
        float dd2 = (c2i==0)?dx:((c2i==1)?dy:dz);
        const bool zw1 = (c0p == 2);            // m=1 uses z1
        const bool zw2 = (c0p == 0);            // m=2 uses z0
        #pragma unroll
        for (int g = 0; g < 3; ++g) {
            int i  = (3*g + p)*16 + sl;         // chunk id
            int q  = i / 3;
            int k0 = i + q;
            const float* zp = srt + k0;         // paired -> ds_read2_b32
            float z0 = zp[0];
            float z1 = zp[1];
            float v0 = fmaf(dd0, z0, o0);
            float v3 = fmaf(dd0, z1, o0);
            float v1 = fmaf(dd1, zw1 ? z1 : z0, o1);
            float v2 = fmaf(dd2, zw2 ? z0 : z1, o2);
            vf4 v = {v0, v1, v2, v3};
            __builtin_nontemporal_store(v, (vf4*)(pbase + 4*i));
        }
    }
}

extern "C" void kernel_launch(void* const* d_in, const int* in_sizes, int n_in,
                              void* d_out, int out_size, void* d_ws, size_t ws_size,
                              hipStream_t stream) {
    const float* org   = (const float*)d_in[0];
    const float* dir   = (const float*)d_in[1];
    const float* dens  = (const float*)d_in[2];
    const float* trand = (const float*)d_in[3];
    const float* uv    = (const float*)d_in[4];
    int B = in_sizes[0] / 3;   // 131072

    float* out_pts = (float*)d_out;
    float* out_z   = out_pts + (size_t)B * 576;

    dim3 grid(B / RPB), block(128);
    hipLaunchKernelGGL(hier_sampler, grid, block, 0, stream,
                       org, dir, dens, trand, uv, out_pts, out_z);
}

// Round 22
// 112.074 us; speedup vs baseline: 1.2390x; 1.0169x over previous
//
#include <hip/hip_runtime.h>

// NeRF hierarchical sampler: 16 lanes per ray, 4 rays per wave64, 2 waves/block.
// Sort = merge decomposition: fine 128 sorted DESCENDING in registers (8/lane),
// then [coarse asc 64][fine desc 128][-1e30 x64] is bitonic -> 8-substage
// ascending bitonic merge at 16/lane. All cross-lane via DPP.
// Search levels 1-4 from REGISTERS: cdfB[4k] lives in lane k (bb), and the
// bisection midpoints at granularity 32/16/8/4 are all multiples of 4 ->
// broadcast nb=bb*itot from 15 lanes once, per-u cndmask select trees.
// Only the last 3 levels (granularity 2,1 + resolve) touch LDS.
// Final cdf/edge lookups as PAIRED ds_read2.
// Emit: 3-phase unroll, o/d selects hoisted per phase (smod = sl%3, one csub).
// Outputs via wave-contiguous nontemporal stores (z routed through LDS).
// Per-ray LDS (RSTR=324 floats, 16B-aligned):
//   [0..191]   srt  : coarse(0..63) + fine-sorted(64..191), later sorted 192
//   [192..255] cdfB : cdf[1..64]
//   [256..320] edg  : 65-entry z_edges   (321..323 = padding, absorbs overreads)
#define RPW 4
#define RPB 8
#define RSTR 324

typedef float vf4 __attribute__((ext_vector_type(4)));

template<int CTRL, bool BC>
__device__ __forceinline__ float updpp(float old, float x) {
    return __int_as_float(__builtin_amdgcn_update_dpp(
        __float_as_int(old), __float_as_int(x), CTRL, 0xF, 0xF, BC));
}

// cross-lane xor within 16-lane row, distance LM in {1,2,4,8}
template<int LM>
__device__ __forceinline__ float xl(float x, const bool lo4) {
    if constexpr (LM == 1)      return updpp<0xB1, true>(0.0f, x);
    else if constexpr (LM == 2) return updpp<0x4E, true>(0.0f, x);
    else if constexpr (LM == 8) return updpp<0x128,true>(0.0f, x);
    else {
        float r4  = updpp<0x124,true>(0.0f, x);   // lane i <- (i-4)&15
        float r12 = updpp<0x12C,true>(0.0f, x);   // lane i <- (i+4)&15
        return lo4 ? r12 : r4;                    // partner i^4
    }
}

#define CE(a, b, dir) { float _lo = fminf(a, b), _hi = fmaxf(a, b); \
                        a = (dir) ? _lo : _hi; b = (dir) ? _hi : _lo; }

// Fine sort substage: 128 elements DESCENDING, 8/lane, e = 8*sl + h.
// Inverted network: asc(e) = ((e&K)!=0); tmin(e) = (asc == ((e&J)==0)).
template<int K, int J>
__device__ __forceinline__ void substageF(float (&f)[8], const int sl) {
    if constexpr (J >= 8) {                      // cross-lane: lm = J/8
        constexpr int lm = J >> 3;
        const bool uasc = ((sl & (K >> 3)) != 0);          // K >= 16 here
        const bool lo4  = ((sl & 4) == 0);
        #pragma unroll
        for (int h = 0; h < 8; ++h) {
            float p = xl<lm>(f[h], lo4);
            const bool tmin = (uasc == ((sl & lm) == 0));
            f[h] = tmin ? fminf(f[h], p) : fmaxf(f[h], p);
        }
    } else {
        bool dirlane = true;
        if constexpr (K == 8)       dirlane = ((sl & 1) != 0);
        else if constexpr (K >= 16) dirlane = ((sl & (K >> 3)) != 0);
        #pragma unroll
        for (int h = 0; h < 8; ++h) {
            if ((h & J) == 0) {
                const int b = h ^ J;
                bool dr;
                if constexpr (K <= 4) dr = ((h & K) != 0);
                else                  dr = dirlane;
                CE(f[h], f[b], dr);
            }
        }
    }
}

// Merge substage: 256 elements, 16/lane, e = 16*sl + h, ascending everywhere.
template<int J>
__device__ __forceinline__ void substageM(float (&y)[16], const int sl) {
    if constexpr (J >= 16) {                     // cross-lane: lm = J/16
        constexpr int lm = J >> 4;
        const bool lo4 = ((sl & 4) == 0);
        #pragma unroll
        for (int h = 0; h < 16; ++h) {
            float p = xl<lm>(y[h], lo4);
            const bool tmin = ((sl & lm) == 0);
            y[h] = tmin ? fminf(y[h], p) : fmaxf(y[h], p);
        }
    } else {
        #pragma unroll
        for (int h = 0; h < 16; ++h) {
            if ((h & J) == 0) {
                const int b = h ^ J;
                CE(y[h], y[b], true);
            }
        }
    }
}

__global__ __launch_bounds__(128) void hier_sampler(
    const float* __restrict__ org, const float* __restrict__ dir,
    const float* __restrict__ dens, const float* __restrict__ trand,
    const float* __restrict__ uu, float* __restrict__ out_pts,
    float* __restrict__ out_z)
{
    const int tid  = threadIdx.x;
    const int sl   = tid & 15;
    const int rloc = tid >> 4;
    const int ray  = blockIdx.x * RPB + rloc;

    __shared__ __align__(16) float lds[RPB * RSTR];
    float* srt  = &lds[rloc * RSTR];
    float* cdfB = srt + 192;
    float* edg  = srt + 256;

    // ---- issue ALL global loads up front ----
    const float4 t4 = ((const float4*)trand)[(size_t)ray * 16 + sl];
    const float4 d4 = ((const float4*)dens )[(size_t)ray * 16 + sl];
    const float4 ua = ((const float4*)uu)[(size_t)ray*32 + 2*sl];
    const float4 ub = ((const float4*)uu)[(size_t)ray*32 + 2*sl + 1];
    const float ox = org[(size_t)ray*3+0], oy = org[(size_t)ray*3+1], oz = org[(size_t)ray*3+2];
    const float dx = dir[(size_t)ray*3+0], dy = dir[(size_t)ray*3+1], dz = dir[(size_t)ray*3+2];

    // ---- coarse stratified sampling: 4 samples/lane, j = 4*sl+m ----
    const float step = 4.0f / 63.0f;
    const float tarr[4] = {t4.x, t4.y, t4.z, t4.w};
    const float darr[4] = {d4.x, d4.y, d4.z, d4.w};
    float zv[4];
    #pragma unroll
    for (int m = 0; m < 4; ++m) {
        int j = 4*sl + m;
        float zg = 2.0f + step * (float)j;
        float lo = (j == 0)  ? 2.0f : (zg - 0.5f*step);
        float up = (j == 63) ? 6.0f : (zg + 0.5f*step);
        zv[m] = lo + (up - lo) * tarr[m];
    }
    float znext0 = updpp<0x101,true>(0.0f, zv[0]);        // shfl_down 1
    float delta[4] = { zv[1]-zv[0], zv[2]-zv[1], zv[3]-zv[2],
                       (sl == 15) ? 1e10f : (znext0 - zv[3]) };

    // ---- transmittance weights (in-lane 4 + cross-lane 16 scans) ----
    float a[4], pp[4];
    {
        float run = 1.0f;
        #pragma unroll
        for (int m = 0; m < 4; ++m) {
            a[m] = 1.0f - __expf(-darr[m] * delta[m]);
            run *= (1.0f - a[m] + 1e-10f);
            pp[m] = run;
        }
    }
    float P = pp[3];
    P *= updpp<0x111,false>(1.0f, P);
    P *= updpp<0x112,false>(1.0f, P);
    P *= updpp<0x114,false>(1.0f, P);
    P *= updpp<0x118,false>(1.0f, P);
    float E = updpp<0x111,false>(1.0f, P);      // exclusive; sl==0 -> 1.0

    float sw[4];
    {
        float acc = 0.0f;
        #pragma unroll
        for (int m = 0; m < 4; ++m) {
            float T = (m == 0) ? E : E * pp[m-1];
            acc += a[m]*T + 1e-5f;
            sw[m] = acc;
        }
    }
    float S = sw[3];
    S += updpp<0x111,false>(0.0f, S);
    S += updpp<0x112,false>(0.0f, S);
    S += updpp<0x114,false>(0.0f, S);
    S += updpp<0x118,false>(0.0f, S);
    float Es  = updpp<0x111,false>(0.0f, S);
    float tot = __shfl(S, 15, 16);
    float itot = 1.0f / tot;

    *(float4*)(cdfB + 4*sl) = make_float4((Es+sw[0])*itot, (Es+sw[1])*itot,
                                          (Es+sw[2])*itot, (Es+sw[3])*itot);
    // all multiples-of-4 cdf values from registers: nb = cdfB[4*sl]
    float nb  = (Es + sw[0]) * itot;
    float c4  = __shfl(nb, 1, 16),  c8  = __shfl(nb, 2, 16);
    float c12 = __shfl(nb, 3, 16),  c16 = __shfl(nb, 4, 16);
    float c20 = __shfl(nb, 5, 16),  c24 = __shfl(nb, 6, 16);
    float c28 = __shfl(nb, 7, 16),  c32 = __shfl(nb, 8, 16);
    float c36 = __shfl(nb, 9, 16),  c40 = __shfl(nb, 10, 16);
    float c44 = __shfl(nb, 11, 16), c48 = __shfl(nb, 12, 16);
    float c52 = __shfl(nb, 13, 16), c56 = __shfl(nb, 14, 16);
    float c60 = __shfl(nb, 15, 16);

    // ---- z_edges ----
    float zp3 = updpp<0x111,true>(0.0f, zv[3]);
    float ej0 = (sl == 0) ? (1.5f*zv[0] - 0.5f*zv[1]) : 0.5f*(zp3 + zv[0]);
    *(float4*)(edg + 4*sl) = make_float4(ej0, 0.5f*(zv[0]+zv[1]),
                                         0.5f*(zv[1]+zv[2]), 0.5f*(zv[2]+zv[3]));
    if (sl == 15) edg[64] = 1.5f*zv[3] - 0.5f*zv[2];
    // ---- stage coarse (merged-elements 0..63, ascending) ----
    *(float4*)(srt + 4*sl) = make_float4(zv[0], zv[1], zv[2], zv[3]);

    // ---- inverse-CDF fine sampling: 8 u's per lane (= fine elems 8sl..8sl+7) --
    // Steps 1-4 from registers (midpoints 32; 48/16; 8..56; 4..60 all mult-4),
    // then 3 LDS steps (granularity 2,1,resolve) + paired finals.
    const float uarr[8] = {ua.x,ua.y,ua.z,ua.w, ub.x,ub.y,ub.z,ub.w};
    float fz[8];
    #pragma unroll
    for (int t = 0; t < 8; ++t) {
        float u = uarr[t];
        bool d0 = (c32 <= u);
        int  lo = d0 ? 33 : 0;
        int  hi = d0 ? 64 : 32;
        float cm2 = d0 ? c48 : c16;
        int  m2 = (lo + hi) >> 1;               // 48 or 16
        bool d1 = (cm2 <= u);
        lo = d1 ? m2 + 1 : lo;
        hi = d1 ? hi : m2;
        float cm3 = d0 ? (d1 ? c56 : c40) : (d1 ? c24 : c8);
        int  m3 = (lo + hi) >> 1;               // 8/24/40/56
        bool d2 = (cm3 <= u);
        lo = d2 ? m3 + 1 : lo;
        hi = d2 ? hi : m3;
        float cm4 = d0 ? (d1 ? (d2 ? c60 : c52) : (d2 ? c44 : c36))
                       : (d1 ? (d2 ? c28 : c20) : (d2 ? c12 : c4));
        int  m4 = (lo + hi) >> 1;               // 4+8k
        bool d3 = (cm4 <= u);
        lo = d3 ? m4 + 1 : lo;
        hi = d3 ? hi : m4;
        #pragma unroll
        for (int it = 0; it < 3; ++it) {
            int m = (lo + hi) >> 1;
            bool c = cdfB[m] <= u;              // early-resolved: c false (safe)
            lo = c ? m+1 : lo;
            hi = c ? hi  : m;
        }
        // finals as paired reads: cb[0],cb[1] and eb[0],eb[1] (ds_read2).
        int c0a = (lo > 0) ? lo - 1 : 0;
        const float* cb = cdfB + c0a;
        float w0 = cb[0], w1 = cb[1];
        float c0v = (lo == 0) ? 0.0f : w0;               // cdf[below]
        float c1v = (lo == 0 || lo == 64) ? w0 : w1;     // cdf[above]
        const float* eb = edg + lo;                      // below = lo
        float x0 = eb[0], x1 = eb[1];
        float e0 = x0;
        float e1 = (lo < 64) ? x1 : x0;                  // above = min(lo+1,64)
        float dn = c1v - c0v;
        if (dn < 1e-5f) dn = 1.0f;
        float tt = (u - c0v) / dn;
        fz[t] = e0 + tt * (e1 - e0);
    }

    // ---- bitonic sort of fine 128 DESCENDING, in registers (8/lane) ----
    substageF<2,1>(fz, sl);
    substageF<4,2>(fz, sl);    substageF<4,1>(fz, sl);
    substageF<8,4>(fz, sl);    substageF<8,2>(fz, sl);    substageF<8,1>(fz, sl);
    substageF<16,8>(fz, sl);   substageF<16,4>(fz, sl);   substageF<16,2>(fz, sl);
    substageF<16,1>(fz, sl);
    substageF<32,16>(fz, sl);  substageF<32,8>(fz, sl);   substageF<32,4>(fz, sl);
    substageF<32,2>(fz, sl);   substageF<32,1>(fz, sl);
    substageF<64,32>(fz, sl);  substageF<64,16>(fz, sl);  substageF<64,8>(fz, sl);
    substageF<64,4>(fz, sl);   substageF<64,2>(fz, sl);   substageF<64,1>(fz, sl);
    substageF<128,64>(fz, sl); substageF<128,32>(fz, sl); substageF<128,16>(fz, sl);
    substageF<128,8>(fz, sl);  substageF<128,4>(fz, sl);  substageF<128,2>(fz, sl);
    substageF<128,1>(fz, sl);

    // stage fine-sorted at merged-elements 64..191
    *(float4*)(srt + 64 + 8*sl)     = make_float4(fz[0],fz[1],fz[2],fz[3]);
    *(float4*)(srt + 64 + 8*sl + 4) = make_float4(fz[4],fz[5],fz[6],fz[7]);

    // ---- load merge layout: y[h] = merged-element 16*sl+h ----
    float y[16];
    if (sl < 12) {
        #pragma unroll
        for (int tq = 0; tq < 4; ++tq) {
            float4 v = *(const float4*)(srt + 16*sl + 4*tq);
            y[4*tq+0]=v.x; y[4*tq+1]=v.y; y[4*tq+2]=v.z; y[4*tq+3]=v.w;
        }
    } else {
        #pragma unroll
        for (int h = 0; h < 16; ++h) y[h] = -1.0e30f;
    }

    // ---- bitonic merge of 256, ascending: 8 substages ----
    substageM<128>(y, sl); substageM<64>(y, sl); substageM<32>(y, sl);
    substageM<16>(y, sl);  substageM<8>(y, sl);  substageM<4>(y, sl);
    substageM<2>(y, sl);   substageM<1>(y, sl);

    // pads (-1e30) occupy elements 0..63; real ranks 0..191 at elements 64..255.
    if (sl >= 4) {
        #pragma unroll
        for (int tq = 0; tq < 4; ++tq) {
            *(float4*)(srt + 16*(sl-4) + 4*tq) =
                make_float4(y[4*tq],y[4*tq+1],y[4*tq+2],y[4*tq+3]);
        }
    }

    // ---- z emit, coalesced: 48 float4 chunks/ray ----
    {
        float* zb = out_z + (size_t)ray * 192;
        #pragma unroll
        for (int it = 0; it < 3; ++it) {
            int c = it * 16 + sl;
            vf4 v = *(const vf4*)(srt + 4*c);
            __builtin_nontemporal_store(v, (vf4*)(zb + 4*c));
        }
    }

    // ---- emit points: 3 phases x 3 iterations; c0 = (smod+p) mod 3 ----
    float* pbase = out_pts + (size_t)ray * 576;
    const int smod = sl % 3;
    #pragma unroll
    for (int p = 0; p < 3; ++p) {
        int c0p = smod + p;
        c0p -= (c0p >= 3) ? 3 : 0;              // (sl+p) mod 3
        float o0  = (c0p==0)?ox:((c0p==1)?oy:oz);
        float dd0 = (c0p==0)?dx:((c0p==1)?dy:dz);
        int   c1i = (c0p==2)?0:(c0p+1);
        float o1  = (c1i==0)?ox:((c1i==1)?oy:oz);
        float dd1 = (c1i==0)?dx:((c1i==1)?dy:dz);
        int   c2i = (c0p==0)?2:(c0p-1);
        float o2  = (c2i==0)?ox:((c2i==1)?oy:oz);
        float dd2 = (c2i==0)?dx:((c2i==1)?dy:dz);
        const bool zw1 = (c0p == 2);            // m=1 uses z1
        const bool zw2 = (c0p == 0);            // m=2 uses z0
        #pragma unroll
        for (int g = 0; g < 3; ++g) {
            int i  = (3*g + p)*16 + sl;         // chunk id
            int q  = i / 3;
            int k0 = i + q;
            const float* zp = srt + k0;         // paired -> ds_read2_b32
            float z0 = zp[0];
            float z1 = zp[1];
            float v0 = fmaf(dd0, z0, o0);
            float v3 = fmaf(dd0, z1, o0);
            float v1 = fmaf(dd1, zw1 ? z1 : z0, o1);
            float v2 = fmaf(dd2, zw2 ? z0 : z1, o2);
            vf4 v = {v0, v1, v2, v3};
            __builtin_nontemporal_store(v, (vf4*)(pbase + 4*i));
        }
    }
}

extern "C" void kernel_launch(void* const* d_in, const int* in_sizes, int n_in,
                              void* d_out, int out_size, void* d_ws, size_t ws_size,
                              hipStream_t stream) {
    const float* org   = (const float*)d_in[0];
    const float* dir   = (const float*)d_in[1];
    const float* dens  = (const float*)d_in[2];
    const float* trand = (const float*)d_in[3];
    const float* uv    = (const float*)d_in[4];
    int B = in_sizes[0] / 3;   // 131072

    float* out_pts = (float*)d_out;
    float* out_z   = out_pts + (size_t)B * 576;

    dim3 grid(B / RPB), block(128);
    hipLaunchKernelGGL(hier_sampler, grid, block, 0, stream,
                       org, dir, dens, trand, uv, out_pts, out_z);
}